// Round 3
// baseline (881.302 us; speedup 1.0000x reference)
//
#include <hip/hip_runtime.h>
#include <hip/hip_bf16.h>

#define SEQ 2305
#define NROWS 4610      // B*SEQ
#define DIM 512
#define QKVN 1536
#define NBS 66          // LDS stride (bf16 elems) for nearby K rows

typedef __attribute__((ext_vector_type(8))) short v8s;
typedef __attribute__((ext_vector_type(4))) float v4f;

__device__ __forceinline__ float wave_max(float x) {
    for (int o = 32; o; o >>= 1) x = fmaxf(x, __shfl_xor(x, o));
    return x;
}
__device__ __forceinline__ float wave_sum(float x) {
    for (int o = 32; o; o >>= 1) x += __shfl_xor(x, o);
    return x;
}

// ---------------- copy + bf16 cast ----------------
__global__ void copy_cast(const float4* __restrict__ in, float4* __restrict__ out,
                          __hip_bfloat16* __restrict__ outb, int n4) {
    int i = blockIdx.x * blockDim.x + threadIdx.x;
    if (i >= n4) return;
    float4 v = in[i];
    out[i] = v;
    int j = i * 4;
    outb[j + 0] = __float2bfloat16(v.x);
    outb[j + 1] = __float2bfloat16(v.y);
    outb[j + 2] = __float2bfloat16(v.z);
    outb[j + 3] = __float2bfloat16(v.w);
}

// ---------------- weight transpose + bf16 convert ----------------
struct WPack { const float* p[12]; };

__global__ void transpose_weights(WPack wp, __hip_bfloat16* __restrict__ wqkv,
                                  __hip_bfloat16* __restrict__ wo) {
    __shared__ float tile[32][33];
    int m = blockIdx.z;
    const float* src = wp.p[m];
    int l = m >> 2, j = m & 3;
    __hip_bfloat16* dst = (j < 3) ? (wqkv + (size_t)l * QKVN * DIM + (size_t)j * DIM * DIM)
                                  : (wo + (size_t)l * DIM * DIM);
    int bx = blockIdx.x * 32, by = blockIdx.y * 32;
    int tx = threadIdx.x, ty = threadIdx.y;
    #pragma unroll
    for (int i = 0; i < 4; i++)
        tile[ty + 8 * i][tx] = src[(size_t)(by + ty + 8 * i) * DIM + bx + tx];
    __syncthreads();
    #pragma unroll
    for (int i = 0; i < 4; i++)
        dst[(size_t)(bx + ty + 8 * i) * DIM + by + tx] = __float2bfloat16(tile[tx][ty + 8 * i]);
}

// ---------------- bf16 MFMA GEMM: C[M,N] = A[M,K] * Bt[N,K]^T (+bias +res, opt bf16 copy) ----------------
__global__ __launch_bounds__(256) void gemm_bf16(
    const __hip_bfloat16* __restrict__ A, const __hip_bfloat16* __restrict__ Bt,
    float* __restrict__ C, const float* __restrict__ bias, const float* __restrict__ res,
    __hip_bfloat16* __restrict__ Cb, int M, int N) {
    const int K = 512;
    int tid = threadIdx.x;
    int wid = tid >> 6, lane = tid & 63;
    int quad = lane >> 4, l16 = lane & 15;
    int waveM = blockIdx.x * 64 + (wid >> 1) * 32;
    int waveN = blockIdx.y * 64 + (wid & 1) * 32;

    const short* As = (const short*)A;
    const short* Bs = (const short*)Bt;

    int rowA0 = waveM + l16;        if (rowA0 >= M) rowA0 = M - 1;
    int rowA1 = waveM + 16 + l16;   if (rowA1 >= M) rowA1 = M - 1;
    int rowB0 = waveN + l16;
    int rowB1 = waveN + 16 + l16;

    const short* a0p = As + (size_t)rowA0 * K + quad * 8;
    const short* a1p = As + (size_t)rowA1 * K + quad * 8;
    const short* b0p = Bs + (size_t)rowB0 * K + quad * 8;
    const short* b1p = Bs + (size_t)rowB1 * K + quad * 8;

    v4f acc00 = {}, acc01 = {}, acc10 = {}, acc11 = {};
    #pragma unroll 4
    for (int k0 = 0; k0 < K; k0 += 32) {
        v8s a0 = *(const v8s*)(a0p + k0);
        v8s a1 = *(const v8s*)(a1p + k0);
        v8s b0 = *(const v8s*)(b0p + k0);
        v8s b1 = *(const v8s*)(b1p + k0);
        acc00 = __builtin_amdgcn_mfma_f32_16x16x32_bf16(a0, b0, acc00, 0, 0, 0);
        acc01 = __builtin_amdgcn_mfma_f32_16x16x32_bf16(a0, b1, acc01, 0, 0, 0);
        acc10 = __builtin_amdgcn_mfma_f32_16x16x32_bf16(a1, b0, acc10, 0, 0, 0);
        acc11 = __builtin_amdgcn_mfma_f32_16x16x32_bf16(a1, b1, acc11, 0, 0, 0);
    }

    v4f accs[2][2] = {{acc00, acc01}, {acc10, acc11}};
    #pragma unroll
    for (int sm = 0; sm < 2; sm++)
        #pragma unroll
        for (int sn = 0; sn < 2; sn++)
            #pragma unroll
            for (int r = 0; r < 4; r++) {
                int row = waveM + sm * 16 + quad * 4 + r;
                int col = waveN + sn * 16 + l16;
                if (row < M) {
                    float v = accs[sm][sn][r];
                    if (bias) v += bias[col];
                    if (res) v += res[(size_t)row * N + col];
                    size_t idx = (size_t)row * N + col;
                    C[idx] = v;
                    if (Cb) Cb[idx] = __float2bfloat16(v);
                }
            }
}

// ---------------- axial attention (typ 0/1) ----------------
__global__ __launch_bounds__(256) void axial_attn(
    const float* __restrict__ qkv, __hip_bfloat16* __restrict__ attn_b, int typ) {
    __shared__ float kl[49 * 65];
    __shared__ float vl[49 * 65];
    __shared__ float pl[4][64];
    int n = blockIdx.x;
    int b = blockIdx.y >> 3, h = blockIdx.y & 7;
    int tid = threadIdx.x;
    size_t baseQ = ((size_t)b * SEQ) * QKVN + h * 64;

    for (int idx = tid; idx < 49 * 64; idx += 256) {
        int j = idx >> 6, d = idx & 63;
        int sp = (j == 0) ? 0 : (typ == 0 ? 1 + n * 48 + (j - 1) : 1 + (j - 1) * 48 + n);
        size_t base = baseQ + (size_t)sp * QKVN + d;
        kl[j * 65 + d] = qkv[base + 512];
        vl[j * 65 + d] = qkv[base + 1024];
    }
    __syncthreads();

    int wave = tid >> 6, lane = tid & 63;
    const float NEG_INF = -__builtin_inff();
    for (int i = 1 + wave; i <= 48; i += 4) {
        int sp = typ == 0 ? 1 + n * 48 + (i - 1) : 1 + (i - 1) * 48 + n;
        const float* qrow = qkv + baseQ + (size_t)sp * QKVN;
        float dot;
        if (lane <= i) {
            float s = 0.f;
            const float* kr = &kl[lane * 65];
            #pragma unroll 8
            for (int d = 0; d < 64; d++) s += qrow[d] * kr[d];
            dot = s * 0.125f;
        } else dot = NEG_INF;
        float m = wave_max(dot);
        float e = __expf(dot - m);
        float ssum = wave_sum(e);
        pl[wave][lane] = e / ssum;
        float acc = 0.f;
        int d = lane;
        for (int j = 0; j <= i; j++) acc += pl[wave][j] * vl[j * 65 + d];
        attn_b[((size_t)b * SEQ + sp) * DIM + h * 64 + d] = __float2bfloat16(acc);
    }
    if (n == 0 && tid < 64) {
        attn_b[((size_t)b * SEQ) * DIM + h * 64 + tid] =
            __float2bfloat16(qkv[baseQ + 1024 + tid]);
    }
}

// ---------------- nearby attention (geometric sparse, LDS-staged K) ----------------
// 2 waves / block of 128; one wave per (qp, b, h).
__global__ __launch_bounds__(128) void nearby_attn(
    const float* __restrict__ qkv, __hip_bfloat16* __restrict__ attn_b) {
    __shared__ __hip_bfloat16 kl[2][100 * NBS];   // 26.4 KB
    __shared__ float ql[2][64];
    __shared__ float pl[2][128];
    __shared__ int kpl[2][128];
    int tid = threadIdx.x;
    int wave = tid >> 6, lane = tid & 63;
    int wgid = blockIdx.x * 2 + wave;
    int qp = wgid >> 4;
    int bh = wgid & 15;
    int b = bh >> 3, h = bh & 7;
    size_t base = ((size_t)b * SEQ) * QKVN + h * 64;
    size_t outIdx = ((size_t)b * SEQ + qp) * DIM + h * 64 + lane;

    if (qp == 0) {   // attends only to itself -> v[0]
        attn_b[outIdx] = __float2bfloat16(qkv[base + 1024 + lane]);
        return;
    }
    if (qp == 2304) {  // all-masked row -> uniform softmax -> mean of all V
        float acc = 0.f;
        for (int j = 0; j < SEQ; j++) acc += qkv[base + (size_t)j * QKVN + 1024 + lane];
        attn_b[outIdx] = __float2bfloat16(acc * (1.0f / 2305.0f));
        return;
    }

    int t = qp >> 8, r = qp & 255, hh = r >> 4, ww = r & 15;
    int t0 = t > 3 ? t - 3 : 0;
    int nc = (t - t0 + 1) * 25;

    // per-lane candidates: c = lane and c = lane+64; -1 = invalid
    int kp1 = -1, kp2 = -1;
    {
        int c = lane;
        if (c < nc) {
            int f = c / 25, pos = c % 25;
            int tt = t0 + f, dy = pos / 5 - 2, dx = pos % 5 - 2;
            int h2 = hh + dy, w2 = ww + dx;
            if (h2 >= 0 && h2 < 16 && w2 >= 0 && w2 < 16 && (tt < t || pos < 12))
                kp1 = tt * 256 + h2 * 16 + w2 + 1;
        }
        c = lane + 64;
        if (c < nc) {
            int f = c / 25, pos = c % 25;
            int tt = t0 + f, dy = pos / 5 - 2, dx = pos % 5 - 2;
            int h2 = hh + dy, w2 = ww + dx;
            if (h2 >= 0 && h2 < 16 && w2 >= 0 && w2 < 16 && (tt < t || pos < 12))
                kp2 = tt * 256 + h2 * 16 + w2 + 1;
        }
    }
    kpl[wave][lane] = kp1;
    kpl[wave][lane + 64] = kp2;
    ql[wave][lane] = qkv[base + (size_t)qp * QKVN + lane];

    // stage valid candidate K rows into LDS, coalesced (lane = d), bf16
    #pragma unroll 4
    for (int c = 0; c < nc; c++) {
        int kp = kpl[wave][c];
        if (kp >= 0)
            kl[wave][c * NBS + lane] =
                __float2bfloat16(qkv[base + (size_t)kp * QKVN + 512 + lane]);
    }

    // dots from LDS (lane = candidate)
    const float NEG_INF = -__builtin_inff();
    float dd0 = NEG_INF, dd1 = NEG_INF;
    if (lane < nc && kp1 >= 0) {
        const unsigned* kr = (const unsigned*)&kl[wave][lane * NBS];
        float sum = 0.f;
        #pragma unroll
        for (int d2 = 0; d2 < 32; d2++) {
            unsigned u = kr[d2];
            sum += ql[wave][2 * d2] * __uint_as_float(u << 16)
                 + ql[wave][2 * d2 + 1] * __uint_as_float(u & 0xffff0000u);
        }
        dd0 = sum * 0.125f;
    }
    if (lane + 64 < nc && kp2 >= 0) {
        const unsigned* kr = (const unsigned*)&kl[wave][(lane + 64) * NBS];
        float sum = 0.f;
        #pragma unroll
        for (int d2 = 0; d2 < 32; d2++) {
            unsigned u = kr[d2];
            sum += ql[wave][2 * d2] * __uint_as_float(u << 16)
                 + ql[wave][2 * d2 + 1] * __uint_as_float(u & 0xffff0000u);
        }
        dd1 = sum * 0.125f;
    }

    float m = wave_max(fmaxf(dd0, dd1));
    float e1 = __expf(dd0 - m), e2 = __expf(dd1 - m);
    float ssum = wave_sum(e1 + e2);
    float inv = 1.0f / ssum;
    pl[wave][lane] = e1 * inv;
    pl[wave][lane + 64] = e2 * inv;

    float acc = 0.f;
    #pragma unroll 4
    for (int c = 0; c < nc; c++) {
        int kc = kpl[wave][c];
        if (kc >= 0)
            acc += pl[wave][c] * qkv[base + (size_t)kc * QKVN + 1024 + lane];
    }
    attn_b[outIdx] = __float2bfloat16(acc);
}

// ---------------- host launch ----------------
extern "C" void kernel_launch(void* const* d_in, const int* in_sizes, int n_in,
                              void* d_out, int out_size, void* d_ws, size_t ws_size,
                              hipStream_t stream) {
    const float* x = (const float*)d_in[0];
    float* xcur = (float*)d_out;

    char* ws = (char*)d_ws;
    size_t off = 0;
    auto alloc = [&](size_t bytes) -> void* {
        void* p = ws + off;
        off = (off + bytes + 255) & ~(size_t)255;
        return p;
    };
    __hip_bfloat16* wqkv  = (__hip_bfloat16*)alloc((size_t)3 * QKVN * DIM * 2);
    __hip_bfloat16* wo    = (__hip_bfloat16*)alloc((size_t)3 * DIM * DIM * 2);
    __hip_bfloat16* xb    = (__hip_bfloat16*)alloc((size_t)NROWS * DIM * 2);
    __hip_bfloat16* attnb = (__hip_bfloat16*)alloc((size_t)NROWS * DIM * 2);
    float* qkv            = (float*)alloc((size_t)NROWS * QKVN * 4);

    const int nElem = NROWS * DIM;
    const int n4 = nElem / 4;

    copy_cast<<<(n4 + 255) / 256, 256, 0, stream>>>((const float4*)x, (float4*)xcur, xb, n4);

    WPack wp;
    for (int l = 0; l < 3; l++)
        for (int j = 0; j < 4; j++)
            wp.p[l * 4 + j] = (const float*)d_in[2 + l * 5 + j];
    transpose_weights<<<dim3(16, 16, 12), dim3(32, 8), 0, stream>>>(wp, wqkv, wo);

    for (int l = 0; l < 3; l++) {
        gemm_bf16<<<dim3((NROWS + 63) / 64, QKVN / 64), 256, 0, stream>>>(
            xb, wqkv + (size_t)l * QKVN * DIM, qkv, nullptr, nullptr, nullptr, NROWS, QKVN);
        if (l < 2)
            axial_attn<<<dim3(48, 16), 256, 0, stream>>>(qkv, attnb, l);
        else
            nearby_attn<<<(SEQ * 16) / 2, 128, 0, stream>>>(qkv, attnb);
        const float* bo = (const float*)d_in[6 + l * 5];
        gemm_bf16<<<dim3((NROWS + 63) / 64, DIM / 64), 256, 0, stream>>>(
            attnb, wo + (size_t)l * DIM * DIM, xcur, bo, xcur, xb, NROWS, DIM);
    }
}

// Round 4
// 742.864 us; speedup vs baseline: 1.1864x; 1.1864x over previous
//
#include <hip/hip_runtime.h>
#include <hip/hip_bf16.h>

#define SEQ 2305
#define NROWS 4610      // B*SEQ
#define MPAD 4736       // NROWS rounded up to 128
#define DIM 512
#define QKVN 1536

typedef __attribute__((ext_vector_type(8))) short v8s;
typedef __attribute__((ext_vector_type(4))) float v4f;

__device__ __forceinline__ float wave_max(float x) {
    for (int o = 32; o; o >>= 1) x = fmaxf(x, __shfl_xor(x, o));
    return x;
}
__device__ __forceinline__ float wave_sum(float x) {
    for (int o = 32; o; o >>= 1) x += __shfl_xor(x, o);
    return x;
}

__device__ __forceinline__ void load_lds16(const void* g, void* l) {
    __builtin_amdgcn_global_load_lds(
        (const __attribute__((address_space(1))) void*)g,
        (__attribute__((address_space(3))) void*)l, 16, 0, 0);
}

// ---------------- copy + bf16 cast ----------------
__global__ void copy_cast(const float4* __restrict__ in, float4* __restrict__ out,
                          __hip_bfloat16* __restrict__ outb, int n4) {
    int i = blockIdx.x * blockDim.x + threadIdx.x;
    if (i >= n4) return;
    float4 v = in[i];
    out[i] = v;
    int j = i * 4;
    outb[j + 0] = __float2bfloat16(v.x);
    outb[j + 1] = __float2bfloat16(v.y);
    outb[j + 2] = __float2bfloat16(v.z);
    outb[j + 3] = __float2bfloat16(v.w);
}

// ---------------- weight transpose + bf16 convert ----------------
struct WPack { const float* p[12]; };

__global__ void transpose_weights(WPack wp, __hip_bfloat16* __restrict__ wqkv,
                                  __hip_bfloat16* __restrict__ wo) {
    __shared__ float tile[32][33];
    int m = blockIdx.z;
    const float* src = wp.p[m];
    int l = m >> 2, j = m & 3;
    __hip_bfloat16* dst = (j < 3) ? (wqkv + (size_t)l * QKVN * DIM + (size_t)j * DIM * DIM)
                                  : (wo + (size_t)l * DIM * DIM);
    int bx = blockIdx.x * 32, by = blockIdx.y * 32;
    int tx = threadIdx.x, ty = threadIdx.y;
    #pragma unroll
    for (int i = 0; i < 4; i++)
        tile[ty + 8 * i][tx] = src[(size_t)(by + ty + 8 * i) * DIM + bx + tx];
    __syncthreads();
    #pragma unroll
    for (int i = 0; i < 4; i++)
        dst[(size_t)(bx + ty + 8 * i) * DIM + by + tx] = __float2bfloat16(tile[tx][ty + 8 * i]);
}

// ---------------- m97-style LDS-staged bf16 GEMM ----------------
// C[M,N] = A[Mpad,512] * Bt[N,512]^T (+bias +res, opt bf16 copy).
// 128x128 tile, 256 thr = 4 waves 2x2, each wave 64x64 via 4x4 mfma 16x16x32.
__global__ __launch_bounds__(256) void gemm_lds(
    const __hip_bfloat16* __restrict__ A, const __hip_bfloat16* __restrict__ Bt,
    float* __restrict__ C, const float* __restrict__ bias, const float* __restrict__ res,
    __hip_bfloat16* __restrict__ Cb, int M, int N) {
    __shared__ short As[128 * 32];   // 8 KB, row-major [128][32]
    __shared__ short Bs[128 * 32];
    const int K = 512;
    int tid = threadIdx.x;
    int wid = tid >> 6, lane = tid & 63;
    int quad = lane >> 4, l16 = lane & 15;
    int bM = blockIdx.x * 128, bN = blockIdx.y * 128;
    int wM = (wid >> 1) * 64, wN = (wid & 1) * 64;

    const short* Ag = (const short*)A;
    const short* Bg = (const short*)Bt;

    int rowA = tid >> 2, cg = tid & 3;   // pass0: 64B/row -> 4 threads per row
    const short* gA0 = Ag + (size_t)(bM + rowA) * K + cg * 8;
    const short* gA1 = Ag + (size_t)(bM + 64 + rowA) * K + cg * 8;
    const short* gB0 = Bg + (size_t)(bN + rowA) * K + cg * 8;
    const short* gB1 = Bg + (size_t)(bN + 64 + rowA) * K + cg * 8;
    // wave-uniform LDS bases (dest = base + lane*16)
    short* lA0 = As + wid * 512;
    short* lA1 = As + 2048 + wid * 512;
    short* lB0 = Bs + wid * 512;
    short* lB1 = Bs + 2048 + wid * 512;

    v4f acc[4][4] = {};
    for (int k0 = 0; k0 < K; k0 += 32) {
        load_lds16(gA0 + k0, lA0);
        load_lds16(gA1 + k0, lA1);
        load_lds16(gB0 + k0, lB0);
        load_lds16(gB1 + k0, lB1);
        __syncthreads();
        v8s af[4], bf[4];
        #pragma unroll
        for (int i = 0; i < 4; i++)
            af[i] = *(const v8s*)(As + (wM + i * 16 + l16) * 32 + quad * 8);
        #pragma unroll
        for (int j = 0; j < 4; j++)
            bf[j] = *(const v8s*)(Bs + (wN + j * 16 + l16) * 32 + quad * 8);
        #pragma unroll
        for (int i = 0; i < 4; i++)
            #pragma unroll
            for (int j = 0; j < 4; j++)
                acc[i][j] = __builtin_amdgcn_mfma_f32_16x16x32_bf16(af[i], bf[j], acc[i][j], 0, 0, 0);
        __syncthreads();
    }

    #pragma unroll
    for (int i = 0; i < 4; i++) {
        int row = bM + wM + i * 16 + quad * 4;
        #pragma unroll
        for (int j = 0; j < 4; j++) {
            int col = bN + wN + j * 16 + l16;
            #pragma unroll
            for (int r = 0; r < 4; r++) {
                int rr = row + r;
                if (rr < M) {
                    float v = acc[i][j][r];
                    if (bias) v += bias[col];
                    if (res) v += res[(size_t)rr * N + col];
                    size_t idx = (size_t)rr * N + col;
                    C[idx] = v;
                    if (Cb) Cb[idx] = __float2bfloat16(v);
                }
            }
        }
    }
}

// ---------------- axial attention (typ 0/1) ----------------
__global__ __launch_bounds__(256) void axial_attn(
    const float* __restrict__ qkv, __hip_bfloat16* __restrict__ attn_b, int typ) {
    __shared__ float kl[49 * 65];
    __shared__ float vl[49 * 65];
    __shared__ float pl[4][64];
    int n = blockIdx.x;
    int b = blockIdx.y >> 3, h = blockIdx.y & 7;
    int tid = threadIdx.x;
    size_t baseQ = ((size_t)b * SEQ) * QKVN + h * 64;

    for (int idx = tid; idx < 49 * 64; idx += 256) {
        int j = idx >> 6, d = idx & 63;
        int sp = (j == 0) ? 0 : (typ == 0 ? 1 + n * 48 + (j - 1) : 1 + (j - 1) * 48 + n);
        size_t base = baseQ + (size_t)sp * QKVN + d;
        kl[j * 65 + d] = qkv[base + 512];
        vl[j * 65 + d] = qkv[base + 1024];
    }
    __syncthreads();

    int wave = tid >> 6, lane = tid & 63;
    const float NEG_INF = -__builtin_inff();
    for (int i = 1 + wave; i <= 48; i += 4) {
        int sp = typ == 0 ? 1 + n * 48 + (i - 1) : 1 + (i - 1) * 48 + n;
        const float* qrow = qkv + baseQ + (size_t)sp * QKVN;
        float dot;
        if (lane <= i) {
            float s = 0.f;
            const float* kr = &kl[lane * 65];
            #pragma unroll 8
            for (int d = 0; d < 64; d++) s += qrow[d] * kr[d];
            dot = s * 0.125f;
        } else dot = NEG_INF;
        float m = wave_max(dot);
        float e = __expf(dot - m);
        float ssum = wave_sum(e);
        pl[wave][lane] = e / ssum;
        float acc = 0.f;
        int d = lane;
        for (int j = 0; j <= i; j++) acc += pl[wave][j] * vl[j * 65 + d];
        attn_b[((size_t)b * SEQ + sp) * DIM + h * 64 + d] = __float2bfloat16(acc);
    }
    if (n == 0 && tid < 64) {
        attn_b[((size_t)b * SEQ) * DIM + h * 64 + tid] =
            __float2bfloat16(qkv[baseQ + 1024 + tid]);
    }
}

// ---------------- nearby attention: all-coalesced, per-candidate wave reduction ----------------
// 4 waves/block of 256; one wave per (qp, b, h). lane = dim everywhere.
__global__ __launch_bounds__(256) void nearby_attn(
    const float* __restrict__ qkv, __hip_bfloat16* __restrict__ attn_b) {
    __shared__ float pl[4][128];
    __shared__ int kpl[4][128];
    int tid = threadIdx.x;
    int wave = tid >> 6, lane = tid & 63;
    int wgid = blockIdx.x * 4 + wave;
    int qp = wgid >> 4;
    int bh = wgid & 15;
    int b = bh >> 3, h = bh & 7;
    size_t base = ((size_t)b * SEQ) * QKVN + h * 64;
    size_t outIdx = ((size_t)b * SEQ + qp) * DIM + h * 64 + lane;

    if (qp == 0) {   // attends only to itself -> v[0]
        attn_b[outIdx] = __float2bfloat16(qkv[base + 1024 + lane]);
        return;
    }
    if (qp == 2304) {  // all-masked row -> uniform softmax -> mean of all V
        float a0 = 0.f, a1 = 0.f, a2 = 0.f, a3 = 0.f;
        const float* vp = qkv + base + 1024 + lane;
        int j = 0;
        for (; j + 4 <= SEQ; j += 4) {
            a0 += vp[(size_t)(j + 0) * QKVN];
            a1 += vp[(size_t)(j + 1) * QKVN];
            a2 += vp[(size_t)(j + 2) * QKVN];
            a3 += vp[(size_t)(j + 3) * QKVN];
        }
        for (; j < SEQ; j++) a0 += vp[(size_t)j * QKVN];
        attn_b[outIdx] = __float2bfloat16((a0 + a1 + a2 + a3) * (1.0f / 2305.0f));
        return;
    }

    int t = qp >> 8, r = qp & 255, hh = r >> 4, ww = r & 15;
    int t0 = t > 3 ? t - 3 : 0;
    int nc = (t - t0 + 1) * 25;

    // per-lane candidate table: c = lane and c = lane+64; -1 = invalid
    int kp1 = -1, kp2 = -1;
    {
        int c = lane;
        if (c < nc) {
            int f = c / 25, pos = c % 25;
            int tt = t0 + f, dy = pos / 5 - 2, dx = pos % 5 - 2;
            int h2 = hh + dy, w2 = ww + dx;
            if (h2 >= 0 && h2 < 16 && w2 >= 0 && w2 < 16 && (tt < t || pos < 12))
                kp1 = tt * 256 + h2 * 16 + w2 + 1;
        }
        c = lane + 64;
        if (c < nc) {
            int f = c / 25, pos = c % 25;
            int tt = t0 + f, dy = pos / 5 - 2, dx = pos % 5 - 2;
            int h2 = hh + dy, w2 = ww + dx;
            if (h2 >= 0 && h2 < 16 && w2 >= 0 && w2 < 16 && (tt < t || pos < 12))
                kp2 = tt * 256 + h2 * 16 + w2 + 1;
        }
    }
    kpl[wave][lane] = kp1;
    kpl[wave][lane + 64] = kp2;
    float qreg = qkv[base + (size_t)qp * QKVN + lane];   // coalesced

    // scores: per-candidate coalesced K-row load + wave reduction
    const float NEG = -__builtin_inff();
    float s0 = NEG, s1 = NEG;
    const float* kbase = qkv + base + 512 + lane;
    #pragma unroll 4
    for (int c = 0; c < nc; c++) {
        int kp = kpl[wave][c];           // LDS broadcast (wave-uniform)
        if (kp >= 0) {
            float kv = kbase[(size_t)kp * QKVN];    // coalesced 256B
            float dot = wave_sum(qreg * kv) * 0.125f;
            if (c < 64) { if (lane == c) s0 = dot; }
            else if (lane == c - 64) s1 = dot;
        }
    }

    float m = wave_max(fmaxf(s0, s1));
    float e0 = __expf(s0 - m), e1 = __expf(s1 - m);
    float inv = 1.0f / wave_sum(e0 + e1);
    pl[wave][lane] = e0 * inv;
    pl[wave][lane + 64] = e1 * inv;

    // PV: coalesced V-row loads
    const float* vbase = qkv + base + 1024 + lane;
    float acc = 0.f;
    #pragma unroll 4
    for (int c = 0; c < nc; c++) {
        int kp = kpl[wave][c];
        if (kp >= 0) acc += pl[wave][c] * vbase[(size_t)kp * QKVN];
    }
    attn_b[outIdx] = __float2bfloat16(acc);
}

// ---------------- host launch ----------------
extern "C" void kernel_launch(void* const* d_in, const int* in_sizes, int n_in,
                              void* d_out, int out_size, void* d_ws, size_t ws_size,
                              hipStream_t stream) {
    const float* x = (const float*)d_in[0];
    float* xcur = (float*)d_out;

    char* ws = (char*)d_ws;
    size_t off = 0;
    auto alloc = [&](size_t bytes) -> void* {
        void* p = ws + off;
        off = (off + bytes + 255) & ~(size_t)255;
        return p;
    };
    __hip_bfloat16* wqkv  = (__hip_bfloat16*)alloc((size_t)3 * QKVN * DIM * 2);
    __hip_bfloat16* wo    = (__hip_bfloat16*)alloc((size_t)3 * DIM * DIM * 2);
    __hip_bfloat16* xb    = (__hip_bfloat16*)alloc((size_t)MPAD * DIM * 2);
    __hip_bfloat16* attnb = (__hip_bfloat16*)alloc((size_t)MPAD * DIM * 2);
    float* qkv            = (float*)alloc((size_t)NROWS * QKVN * 4);

    const int nElem = NROWS * DIM;
    const int n4 = nElem / 4;

    copy_cast<<<(n4 + 255) / 256, 256, 0, stream>>>((const float4*)x, (float4*)xcur, xb, n4);

    WPack wp;
    for (int l = 0; l < 3; l++)
        for (int j = 0; j < 4; j++)
            wp.p[l * 4 + j] = (const float*)d_in[2 + l * 5 + j];
    transpose_weights<<<dim3(16, 16, 12), dim3(32, 8), 0, stream>>>(wp, wqkv, wo);

    for (int l = 0; l < 3; l++) {
        gemm_lds<<<dim3(MPAD / 128, QKVN / 128), 256, 0, stream>>>(
            xb, wqkv + (size_t)l * QKVN * DIM, qkv, nullptr, nullptr, nullptr, NROWS, QKVN);
        if (l < 2)
            axial_attn<<<dim3(48, 16), 256, 0, stream>>>(qkv, attnb, l);
        else
            nearby_attn<<<(SEQ * 16) / 4, 256, 0, stream>>>(qkv, attnb);
        const float* bo = (const float*)d_in[6 + l * 5];
        gemm_lds<<<dim3(MPAD / 128, DIM / 128), 256, 0, stream>>>(
            attnb, wo + (size_t)l * DIM * DIM, xcur, bo, xcur, xb, NROWS, DIM);
    }
}